// Round 5
// baseline (92.031 us; speedup 1.0000x reference)
//
#include <hip/hip_runtime.h>

// ---------------------------------------------------------------------------
// KAN conv layer: out[b,o,i,j] = sum_{c,p} silu(patch)*bw[o,c,p]
//                              + sum_{c,p,g} Bspline_g(patch)*sw[o,c,p,g]*sc[o,c,p]
// B=16 CIN=32 COUT=64 H=W=64 K=3 -> Ho=Wo=62, P=9, G+k=8 bases
// Implicit GEMM. Spline K=2304 fp8; silu K=288 bf16.
// R8  (103.6us): fp8 spline, dbuf LDS stages, matrix-pipe-bound.
// R9  (102.3us): spline -> 2x MX-scaled K=128 supersteps + 1 fp8 K=32 step.
// R10 (93.7us):  sparse de Boor (4 nonzero bases) + wpack fused into feature.
// R11 (92.0us):  features fused INTO k_gemm.
// R13 (91.5us):  deep feature pipeline + coalesced wpack + setprio (~null ->
//                feature math is only ~1.2us chip-wide, as recalibrated).
// R14: occupancy 2->4 waves/SIMD. 16 waves (1024 thr), wave = (r=w>>2 row,
//      ohq=w&3 o-quarter of 16), acc[4] per wave; per-wave MFMA halves,
//      block totals unchanged. Doubles latency hiding for the ds_read->MFMA
//      dependency chains and L2 staging between the per-period barriers.
//      Staging chunk spread re-distributed over 16 waves. If this nulls,
//      the remaining time is harness fill floor -> roofline.
// ---------------------------------------------------------------------------

typedef short v8s __attribute__((ext_vector_type(8)));
typedef float v4f __attribute__((ext_vector_type(4)));
typedef int   v4i __attribute__((ext_vector_type(4)));
typedef int   v8i __attribute__((ext_vector_type(8)));

#define WMX_OFF     20972032u      // 8*2*4*2*64*16 = 131,072 (MX spline w)
#define WF8_OFF     21103104u      // 8*4*64*8 = 16,384 (leftover fp8 w)
#define WPACKS_OFF  21119488u      // 9*4*64*16 = 36,864 (bf16 silu w)

#define SCALE1 0x7F7F7F7Fu         // E8M0 127 = 1.0 in every byte

__device__ __forceinline__ unsigned short f2bf(float f) {
  unsigned int u = __float_as_uint(f);
  u += 0x7fffu + ((u >> 16) & 1u);          // round-to-nearest-even
  return (unsigned short)(u >> 16);
}

// ---- kernel 1: pack weights, read-coalesced --------------------------------
__global__ __launch_bounds__(256) void k_wpack(const float* __restrict__ bw,
                                               const float* __restrict__ sw,
                                               const float* __restrict__ sc,
                                               unsigned char* __restrict__ ws) {
  const int bid = blockIdx.x, t = threadIdx.x;
  if (bid < 72) {                          // spline: thread per (o,c,p_tap)
    const int idx = bid * 256 + t;         // 0..18431 == (o*32+c)*9 + p_tap
    const int o = idx / 288, rem = idx - o * 288;
    const int c = rem / 9, p_tap = rem - c * 9;
    const float scv = sc[idx];
    const float4 v0 = *(const float4*)(sw + (size_t)idx * 8);
    const float4 v1 = *(const float4*)(sw + (size_t)idx * 8 + 4);
    unsigned lo = __builtin_amdgcn_cvt_pk_fp8_f32(v0.x * scv, v0.y * scv, 0, false);
    lo = __builtin_amdgcn_cvt_pk_fp8_f32(v0.z * scv, v0.w * scv, lo, true);
    unsigned hi = __builtin_amdgcn_cvt_pk_fp8_f32(v1.x * scv, v1.y * scv, 0, false);
    hi = __builtin_amdgcn_cvt_pk_fp8_f32(v1.z * scv, v1.w * scv, hi, true);
    const int di = p_tap / 3, dj = p_tap - di * 3;
    const int k0 = 24 * (c * 3 + di) + 8 * dj;       // k0 % 16 in {0,8}
    const int p = k0 / 288, r288 = k0 - p * 288;
    const int ot = o >> 4, ol = o & 15;
    size_t dst;
    if (r288 < 256) {                      // WMX [p][ss][ot][pc][lane][16]
      const int ss = r288 >> 7, r128 = r288 & 127;
      const int lh = r128 >> 5, r32 = r128 & 31;
      const int pc = r32 >> 4, bh = r32 & 15;        // bh in {0,8}
      dst = WMX_OFF + p * 16384 + ss * 8192 + ot * 2048 + pc * 1024 +
            (lh * 16 + ol) * 16 + bh;
    } else {                               // WF8 [p][ot][lane][8]
      const int r2 = r288 - 256;
      dst = WF8_OFF + p * 2048 + ot * 512 + ((r2 >> 3) * 16 + ol) * 8;
    }
    *(unsigned long long*)(ws + dst) =
        (unsigned long long)lo | ((unsigned long long)hi << 32);
  } else {                                 // silu bf16: thread per (o,cc)
    const int idx2 = (bid - 72) * 256 + t;
    if (idx2 >= 2048) return;
    const int o = idx2 >> 5, cc = idx2 & 31;
    const int ot = o >> 4;
    const int lane = ((cc >> 3) << 4) | (o & 15);
    const int e = cc & 7;
#pragma unroll
    for (int sp = 0; sp < 9; ++sp) {
      const float val = bw[(size_t)(o * 32 + cc) * 9 + sp];
      *(unsigned short*)(ws + WPACKS_OFF + sp * 4096 + ot * 1024 + lane * 16 + e * 2) =
          f2bf(val);
    }
  }
}

// ---- async 16B global -> LDS (lds dest = wave-uniform base + lane*16) ------
__device__ __forceinline__ void ld16(unsigned char* ldsp, const unsigned char* gp) {
  __builtin_amdgcn_global_load_lds(
      (const __attribute__((address_space(1))) unsigned int*)gp,
      (__attribute__((address_space(3))) unsigned int*)ldsp, 16, 0, 0);
}

// ---- kernel 2: fused features + implicit GEMM ------------------------------
// Block: 16 waves = (r = w>>2 of 4 rows, ohq = w&3 o-quarter), 256 blocks
// (1/CU, 4 waves/SIMD). Period p: 2 MX supersteps (K=128) + 1 fp8 K=32 step.
__global__ __launch_bounds__(1024) void k_gemm(const unsigned char* __restrict__ ws,
                                               const float* __restrict__ x,
                                               float* __restrict__ out) {
  __shared__ __align__(16) unsigned char wl8[2][18432];
  __shared__ __align__(16) unsigned char fl8[2][12544];
  __shared__ __align__(16) unsigned char wsil[36864];
  __shared__ __align__(16) unsigned char fsil[25088];

  const int blk = blockIdx.x;              // b*16 + ig
  const int b = blk >> 4, ig = blk & 15;
  const int i0 = ig * 4;
  const int tid = threadIdx.x;
  const int wave = tid >> 6, lane = tid & 63;
  const int q = lane >> 4, ln = lane & 15;
  const int r = wave >> 2, ohq = wave & 3;
  const int i = i0 + r;

  // feature-compute assignment: threads 0..383 own (row 0..5, x 0..63),
  // all 4 channels of the period.
  const bool factive = tid < 384;
  const int frow = tid >> 6, fx = tid & 63;
  const int fy = min(i0 + frow, 63);       // clamp: rows >=64 only feed i>=62 (discarded)

  auto stage_w = [&](int p, int bi) {      // 18 weight chunks over 16 waves
#pragma unroll
    for (int it = 0; it < 2; ++it) {
      const int u = wave + it * 16;
      if (u < 16) {
        ld16(&wl8[bi][u * 1024], ws + WMX_OFF + (size_t)p * 16384 + (size_t)u * 1024 + lane * 16);
      } else if (u < 18) {
        ld16(&wl8[bi][u * 1024], ws + WF8_OFF + (size_t)p * 2048 + (size_t)(u - 16) * 1024 + lane * 16);
      }
    }
  };

  auto stage_wsil = [&]() {                // 36 chunks over 16 waves
#pragma unroll
    for (int it = 0; it < 3; ++it) {
      const int u = wave + it * 16;
      if (u < 36) ld16(&wsil[u * 1024], ws + WPACKS_OFF + (size_t)u * 1024 + lane * 16);
    }
  };

  auto feat_load = [&](int p, float* v) {  // issue x loads (latency hides under MFMA)
    if (factive) {
#pragma unroll
      for (int cp = 0; cp < 4; ++cp)
        v[cp] = x[((size_t)(b * 32 + p * 4 + cp) * 64 + fy) * 64 + fx];
    }
  };

  auto feat_store = [&](int p, int bi, const float* v) {  // de Boor + ds_write
    if (factive) {
      unsigned long long spl[4];
      unsigned short hh[4];
#pragma unroll
      for (int cp = 0; cp < 4; ++cp) {
        const float vv = v[cp];
        hh[cp] = f2bf(vv / (1.0f + __expf(-vv)));        // silu
        // sparse cubic B-spline: knots t_i = -2.2 + 0.4*i; 4 nonzero bases.
        float s = (vv + 2.2f) * 2.5f;
        int ii = (int)floorf(s);
        ii = ii < 0 ? 0 : (ii > 10 ? 10 : ii);
        const float uu = (vv + 2.2f) - 0.4f * (float)ii; // in [0, 0.4)
        float N0 = (0.4f - uu) * 2.5f;
        float N1 = uu * 2.5f;
        float a0 = N0 * 1.25f, a1 = N1 * 1.25f;
        N0 = (0.4f - uu) * a0;
        float N2 = uu * a1;
        N1 = (uu + 0.4f) * a0 + (0.8f - uu) * a1;
        float c0 = N0 * (1.0f / 1.2f), c1 = N1 * (1.0f / 1.2f), c2 = N2 * (1.0f / 1.2f);
        N0 = (0.4f - uu) * c0;
        float N3 = uu * c2;
        N1 = (uu + 0.8f) * c0 + (0.8f - uu) * c1;
        N2 = (uu + 0.4f) * c1 + (1.2f - uu) * c2;
        unsigned w0 = __builtin_amdgcn_cvt_pk_fp8_f32(N0, N1, 0, false);
        w0 = __builtin_amdgcn_cvt_pk_fp8_f32(N2, N3, w0, true);
        unsigned long long wd = w0;
        const int sh = ii * 8 - 24;        // bytes i0-3..i0; out-of-range drops off
        wd = (sh >= 0) ? (wd << sh) : (wd >> (-sh));
        if (!(vv >= -2.2f && vv < 2.2f)) wd = 0;
        spl[cp] = wd;
      }
#pragma unroll
      for (int cp = 0; cp < 4; ++cp)
        *(unsigned long long*)(&fl8[bi][cp * 3072 + frow * 512 + fx * 8]) = spl[cp];
      // silu bf16, swizzled layout matching the silu-phase reads
      unsigned long long sp = (unsigned long long)((unsigned)hh[0] | ((unsigned)hh[1] << 16)) |
                              ((unsigned long long)((unsigned)hh[2] | ((unsigned)hh[3] << 16)) << 32);
      *(unsigned long long*)(&fsil[frow * 4096 + fx * 64 +
                                   (((p >> 1) ^ (fx & 3)) * 16) + (p & 1) * 8]) = sp;
    }
  };

  // feature run offsets: off(sg, qq) for rid = 4*sg+qq
  auto offf = [&](int sg, int qq) {
    int rid = 4 * sg + qq;
    int ch = rid / 3, sub = rid - ch * 3;
    int cp = ch / 3, di = ch - cp * 3;
    return cp * 3072 + (r + di) * 512 + (sub + ln) * 8;
  };
  int offA[4], offB[4];
#pragma unroll
  for (int qq = 0; qq < 4; ++qq) { offA[qq] = offf(q, qq); offB[qq] = offf(4 + q, qq); }
  const int off8 = offf(8, q);

  v4f acc[4];
#pragma unroll
  for (int c = 0; c < 4; ++c) acc[c] = (v4f){0.f, 0.f, 0.f, 0.f};

  // prologue: x loads for periods 0,1 first (longest latency), then weight
  // staging, then de Boor for period 0.
  float v0[4], vcur[4];
  float vnext[4] = {0.f, 0.f, 0.f, 0.f};
  feat_load(0, v0);
  feat_load(1, vcur);
  stage_wsil();
  stage_w(0, 0);
  feat_store(0, 0, v0);
  __syncthreads();

#pragma unroll 1
  for (int t = 0; t < 8; ++t) {
    // top-of-loop: finish period t+1 features (writes fl8[(t+1)&1], which no
    // one reads this iteration) and issue period t+2 x loads + t+1 weights.
    if (t < 7) {
      feat_store(t + 1, (t + 1) & 1, vcur);
      stage_w(t + 1, (t + 1) & 1);
    }
    if (t < 6) feat_load(t + 2, vnext);

    const unsigned char* wb = wl8[t & 1];
    const unsigned char* fb = fl8[t & 1];
    __builtin_amdgcn_s_setprio(1);
#pragma unroll
    for (int ss = 0; ss < 2; ++ss) {
      union { v8i v; v4i h[2]; } wf;
      {
        const unsigned char* wp = wb + ss * 8192 + ohq * 2048 + lane * 16;
        wf.h[0] = *(const v4i*)(wp);
        wf.h[1] = *(const v4i*)(wp + 1024);
      }
      const int* offs = ss ? offB : offA;
      union { v8i v; long l[4]; } ff[4];
#pragma unroll
      for (int pt = 0; pt < 4; ++pt)
#pragma unroll
        for (int qq = 0; qq < 4; ++qq)
          ff[pt].l[qq] = *(const long*)(fb + offs[qq] + pt * 128);
#pragma unroll
      for (int pt = 0; pt < 4; ++pt)
        acc[pt] = __builtin_amdgcn_mfma_scale_f32_16x16x128_f8f6f4(
            wf.v, ff[pt].v, acc[pt], 0, 0, 0, SCALE1, 0, SCALE1);
    }
    {                                      // leftover fp8 K=32 step (sg=8)
      long w8, f8[4];
      w8 = *(const long*)(wb + 16384 + ohq * 512 + lane * 8);
#pragma unroll
      for (int pt = 0; pt < 4; ++pt)
        f8[pt] = *(const long*)(fb + off8 + pt * 128);
#pragma unroll
      for (int pt = 0; pt < 4; ++pt)
        acc[pt] = __builtin_amdgcn_mfma_f32_16x16x32_fp8_fp8(
            w8, f8[pt], acc[pt], 0, 0, 0);
    }
    __builtin_amdgcn_s_setprio(0);
    if (t < 6) {
#pragma unroll
      for (int cp = 0; cp < 4; ++cp) vcur[cp] = vnext[cp];
    }
    __syncthreads();
  }

  // ---- silu phase: bf16, from in-block-computed buffers --------------------
#pragma unroll
  for (int e = 0; e < 9; ++e) {
    const int di = e / 3, dj = e % 3;
    v8s wb2, fb2[4];
    wb2 = *(const v8s*)(&wsil[0] + e * 4096 + ohq * 1024 + lane * 16);
    const int xb = dj + ln;
    const int sbase = (r + di) * 4096 + xb * 64 + ((q ^ (xb & 3)) * 16);
#pragma unroll
    for (int pt = 0; pt < 4; ++pt)
      fb2[pt] = *(const v8s*)(&fsil[0] + sbase + pt * 1024);
    __builtin_amdgcn_s_setprio(1);
#pragma unroll
    for (int pt = 0; pt < 4; ++pt)
      acc[pt] = __builtin_amdgcn_mfma_f32_16x16x32_bf16(
          wb2, fb2[pt], acc[pt], 0, 0, 0);
    __builtin_amdgcn_s_setprio(0);
  }

  // ---- epilogue: C/D layout col(n=j)=lane&15, row(m=o)=q*4+reg -------------
  if (i < 62) {
#pragma unroll
    for (int pt = 0; pt < 4; ++pt) {
      const int j = pt * 16 + ln;
      if (j < 62) {
#pragma unroll
        for (int rr = 0; rr < 4; ++rr) {
          const int o = ohq * 16 + q * 4 + rr;
          out[(((size_t)b * 64 + o) * 62 + i) * 62 + j] = acc[pt][rr];
        }
      }
    }
  }
}

extern "C" void kernel_launch(void* const* d_in, const int* in_sizes, int n_in,
                              void* d_out, int out_size, void* d_ws, size_t ws_size,
                              hipStream_t stream) {
  const float* x  = (const float*)d_in[0];
  const float* bw = (const float*)d_in[1];
  const float* sw = (const float*)d_in[2];
  const float* sc = (const float*)d_in[3];
  unsigned char* ws = (unsigned char*)d_ws;
  float* out = (float*)d_out;

  hipLaunchKernelGGL(k_wpack, dim3(80),  dim3(256),  0, stream, bw, sw, sc, ws);
  hipLaunchKernelGGL(k_gemm,  dim3(256), dim3(1024), 0, stream, ws, x, out);
}